// Round 1
// baseline (76.918 us; speedup 1.0000x reference)
//
#include <hip/hip_runtime.h>

#define HOP 512
#define MAX_NHAR 128
#define N_MAX 4410
#define SEGS 8
#define SM_N 4424               // N_MAX + 8 zero-pad slots (covers padded last-seg reads)
#define PI_D 3.14159265358979323846

// ---------------------------------------------------------------------------
// R10 structure (75.3us, absmax 0.0) + phase-4 transcendental rework.
// Session findings baked into this shape:
//  - Direct harmonic DFT via dual-stream real Goertzel (2 fp64 ops/sample/
//    stream) replaces the reference's Bluestein FFT (~50x less work).
//  - Full fusion (stage+Goertzel+combine in one launch) beats every split.
//  - Static 1024-block grid at full residency (512 thr, launch_bounds(512,8)
//    -> 64 VGPR -> 4 blocks/CU) beats all dynamic schemes (R8/R9/R11/R12).
//  - fp64 EVERYWHERE is mandatory: output passes through atan2; error budget
//    ~1e-8 abs. fp64-level perturbations (<=1e-13) keep absmax at 0.0.
// NEW this round:
//  - Phase 4 no longer calls sincos on LARGE arguments (omega*chunk and
//    omega*(endlast-1) reach ~3000 rad -> OCML f64 slow-path argument
//    reduction, with per-lane args straddling fast/slow branches ->
//    divergent dual execution). Instead: one small-arg sincos gives
//    Z = e^{-i omega}; Q = Z^chunk and P_last = Z^(endlast-1) come from a
//    JOINT binary-exponentiation sharing one squaring chain (~12
//    wave-uniform iterations, scalar branches, ~90 fp64 FMAs). Angle error
//    ~exponent*ulp ~ 3e-13 rad << fp32 ulp; absmax stays 0.0.
//  - w/nhar pinned scalar via readfirstlane (block-uniform by construction).
// Phases: (1) coalesced fp64 Blackman staging into LDS + cos table;
// (2) wave s = dual-stream Goertzel on segment s (k=lane, k+64; each sample
// broadcast-read once); (3) partials via LDS (aliased); (4) tid<128 combines
// with the SEGS-parametric padded-segment rotation algebra, scale, amp/phase.
// ---------------------------------------------------------------------------
__device__ __forceinline__ void frame_params(double f0v, int& w, int& nhar, double& theta) {
    double f0d = f0v < 40.0 ? 40.0 : f0v;
    const double inv = 44100.0 / f0d;
    nhar = (int)fmin(floor(inv * 0.5), 128.0);
    w = 2 * (int)rint(inv * 2.0);
    if (w > N_MAX) w = N_MAX;
    theta = (2.0 * PI_D * f0d) / 44100.0;
}

__global__ __launch_bounds__(512, 8) void czt_fused_kernel(
    const float* __restrict__ x, const float* __restrict__ f0,
    float* __restrict__ out, int t, int F)
{
    __shared__ double sm[SM_N];          // staged frame; first 16 KB reused for partials
    __shared__ double cc[MAX_NHAR];      // cos(theta*(k+1))
    const int tid  = threadIdx.x;        // 0..511
    const int wave = tid >> 6;           // 0..7 == segment id
    const int lane = tid & 63;

    const int frame = blockIdx.x;
    int w, nhar; double theta;
    frame_params((double)f0[frame], w, nhar, theta);
    w    = __builtin_amdgcn_readfirstlane(w);      // block-uniform -> pin scalar
    nhar = __builtin_amdgcn_readfirstlane(nhar);
    const int chunk = (((w + SEGS - 1) / SEGS) + 7) & ~7;   // per-seg span, x8

    // ---- phase 1: stage windowed frame (coalesced), zero pad, cos table ----
    {
        const double c2pi_invw = (2.0 * PI_D) / (double)w;
        const int base = frame * HOP - (w >> 1);             // pad offset cancels
        for (int j = tid; j < w; j += 512) {
            const int ix = base + j;
            const double val = (ix >= 0 && ix < t) ? (double)x[ix] : 0.0;
            const double c1 = cos(c2pi_invw * (double)j);
            // 0.42 - 0.5 c + 0.08 (2c^2-1) = 0.34 - 0.5 c + 0.16 c^2
            const double win = fma(0.16, c1 * c1, 0.34) - 0.5 * c1;
            sm[j] = val * win;
        }
        if (tid < 8) sm[w + tid] = 0.0;                      // padded last-seg reads
        if (tid < MAX_NHAR) cc[tid] = cos(theta * (double)(tid + 1));
    }
    __syncthreads();

    // ---- phase 2: dual-stream Goertzel on this wave's segment ----
    const int j0 = wave * chunk;
    int lenp = 0;
    if (j0 < w) {
        const int l = w - j0;
        lenp = (l > chunk) ? chunk : ((l + 7) & ~7);         // padded length (x8)
    }
    const double Ca = 2.0 * cc[lane];
    const double Cb = 2.0 * cc[lane + 64];
    double s1a = 0.0, s2a = 0.0, s1b = 0.0, s2b = 0.0;
    const double2* __restrict__ sm2 = (const double2*)(sm + j0);  // j0 x8 -> 16B aligned

    if (nhar > 64) {
        for (int jb = 0; jb < lenp; jb += 8) {
            const int h = jb >> 1;
            const double2 v0 = sm2[h], v1 = sm2[h + 1], v2 = sm2[h + 2], v3 = sm2[h + 3];
            const double xv[8] = {v0.x, v0.y, v1.x, v1.y, v2.x, v2.y, v3.x, v3.y};
            #pragma unroll
            for (int u = 0; u < 8; ++u) {
                const double na = fma(Ca, s1a, xv[u] - s2a);
                const double nb = fma(Cb, s1b, xv[u] - s2b);
                s2a = s1a; s1a = na;
                s2b = s1b; s1b = nb;
            }
        }
    } else {
        // harmonics 65..128 all masked for this frame: single stream
        for (int jb = 0; jb < lenp; jb += 8) {
            const int h = jb >> 1;
            const double2 v0 = sm2[h], v1 = sm2[h + 1], v2 = sm2[h + 2], v3 = sm2[h + 3];
            const double xv[8] = {v0.x, v0.y, v1.x, v1.y, v2.x, v2.y, v3.x, v3.y};
            #pragma unroll
            for (int u = 0; u < 8; ++u) {
                const double na = fma(Ca, s1a, xv[u] - s2a);
                s2a = s1a; s1a = na;
            }
        }
    }
    __syncthreads();                      // all waves done READING sm

    // ---- phase 3: partials through LDS (alias over staging buffer) ----
    double2* parts = (double2*)sm;        // [seg][k] double2: 8*128*16B = 16 KB
    parts[wave * MAX_NHAR + lane]      = make_double2(s1a, s2a);
    parts[wave * MAX_NHAR + lane + 64] = make_double2(s1b, s2b);  // zeros if 1-stream
    __syncthreads();

    // ---- phase 4: combine (verified rotation algebra), amp/phase ----
    if (tid < MAX_NHAR) {
        const int slast = (w - 1) / chunk;
        const int endlast = slast * chunk + (((w - slast * chunk) + 7) & ~7);
        const double omega = theta * (double)(tid + 1);

        // Z = e^{-i omega}; the ONLY sincos (small arg: omega <= ~7.3 rad).
        double sw, cw; sincos(omega, &sw, &cw);
        const double Zr = cw, Zi = -sw;

        // Joint binary exponentiation on a shared squaring chain:
        //   Qc = Z^chunk, Pl = Z^(endlast-1).
        // chunk/endlast are frame-uniform -> scalar branches, no divergence.
        double Qr = 1.0, Qi = 0.0, Plr = 1.0, Pli = 0.0;
        double br = Zr, bi = Zi;
        int e1 = chunk, e2 = endlast - 1;
        while (e1 | e2) {
            if (e1 & 1) {
                const double tq = fma(Qr, br, -Qi * bi);
                Qi = fma(Qr, bi, Qi * br); Qr = tq;
            }
            if (e2 & 1) {
                const double tp = fma(Plr, br, -Pli * bi);
                Pli = fma(Plr, bi, Pli * br); Plr = tp;
            }
            e1 >>= 1; e2 >>= 1;
            if (e1 | e2) {
                const double tb = fma(br, br, -bi * bi);
                bi = 2.0 * br * bi; br = tb;
            }
        }

        // R = Z^(chunk-1) = Qc * conj(Z)   (|Z| = 1 to ulp)
        double Rr = fma(Qr, Zr, Qi * Zi);
        double Ri = fma(Qi, Zr, -Qr * Zi);

        double yr = 0.0, yi = 0.0;
        #pragma unroll
        for (int s = 0; s < SEGS; ++s) {
            const double2 v = parts[s * MAX_NHAR + tid];
            const double tr = fma(-cw, v.y, v.x);                // s1 - cw*s2
            const double ti = sw * v.y;                          // + i sw*s2
            const double Pr = (s == slast) ? Plr : Rr;
            const double Pi = (s == slast) ? Pli : Ri;
            yr = fma(Pr, tr, fma(-Pi, ti, yr));
            yi = fma(Pr, ti, fma( Pi, tr, yi));
            const double nr = fma(Rr, Qr, -Ri * Qi);             // R *= Qc
            Ri = fma(Rr, Qi, Ri * Qr); Rr = nr;
        }
        const double scale = 2.381 / (double)((w >> 1) + 1);
        yr *= scale; yi *= scale;

        float ampl = 0.0f, ph = 0.0f;
        if (tid < nhar) {
            ampl = (float)sqrt(yr * yr + yi * yi);
            ph   = (float)atan2(yi, yr);
        }
        out[tid * F + frame] = ampl;                 // ampl  (MAX_NHAR, F)
        out[MAX_NHAR * F + tid * F + frame] = ph;    // phase (MAX_NHAR, F)
    }
}

extern "C" void kernel_launch(void* const* d_in, const int* in_sizes, int n_in,
                              void* d_out, int out_size, void* d_ws, size_t ws_size,
                              hipStream_t stream) {
    const float* x  = (const float*)d_in[0];
    const float* f0 = (const float*)d_in[1];
    float* out = (float*)d_out;
    const int t = in_sizes[0];   // samples
    const int F = in_sizes[1];   // frames
    czt_fused_kernel<<<F, 512, 0, stream>>>(x, f0, out, t, F);
}